// Round 5
// baseline (605.218 us; speedup 1.0000x reference)
//
#include <hip/hip_runtime.h>

#define LL 384
#define NH 8

typedef const float* fp32p;

// ---------------- K1: projections + point rotation ----------------
// 4 rows per block, block 128, grid 192
__global__ __launch_bounds__(128) void k_proj(
    fp32p x, fp32p r, fp32p tvec,
    fp32p Wqs, fp32p Wks, fp32p Wvs,
    fp32p Wqp, fp32p Wkp, fp32p Wvp,
    float* qs, float* ks, float* vs,
    float* qp, float* kp, float* vp)
{
  int t = threadIdx.x;
  int bl0 = blockIdx.x * 4;
  __shared__ float xs[4][128];
  __shared__ float yq[4][96], yk[4][96], yv[4][96];
  #pragma unroll
  for (int rr = 0; rr < 4; ++rr) xs[rr][t] = x[(bl0 + rr)*128 + t];
  __syncthreads();
  float aq[4] = {0,0,0,0}, ak[4] = {0,0,0,0}, av[4] = {0,0,0,0};
  float pq[4] = {0,0,0,0}, pk[4] = {0,0,0,0}, pv[4] = {0,0,0,0};
  bool pt_act = (t < 96);
  for (int d = 0; d < 128; ++d) {
    float wq = Wqs[d*128 + t], wk = Wks[d*128 + t], wv = Wvs[d*128 + t];
    #pragma unroll
    for (int rr = 0; rr < 4; ++rr) {
      float xv = xs[rr][d];
      aq[rr] += xv*wq; ak[rr] += xv*wk; av[rr] += xv*wv;
    }
    if (pt_act) {
      float uq = Wqp[d*96 + t], uk = Wkp[d*96 + t], uv = Wvp[d*96 + t];
      #pragma unroll
      for (int rr = 0; rr < 4; ++rr) {
        float xv = xs[rr][d];
        pq[rr] += xv*uq; pk[rr] += xv*uk; pv[rr] += xv*uv;
      }
    }
  }
  int n = t >> 4, dhs = t & 15;
  #pragma unroll
  for (int rr = 0; rr < 4; ++rr) {
    int bl = bl0 + rr;
    int b = bl / LL, l = bl - (bl / LL)*LL;
    int rowbase = (b*NH + n)*LL + l;
    qs[rowbase*16 + dhs] = aq[rr];
    ks[rowbase*16 + dhs] = ak[rr];
    vs[rowbase*16 + dhs] = av[rr];
  }
  if (pt_act) {
    #pragma unroll
    for (int rr = 0; rr < 4; ++rr) { yq[rr][t] = pq[rr]; yk[rr][t] = pk[rr]; yv[rr][t] = pv[rr]; }
  }
  __syncthreads();
  if (pt_act) {
    int np = t / 12;
    int rem = t - np*12;
    int p = rem / 3, c = rem - p*3;
    int base = np*12 + p*3;
    #pragma unroll
    for (int rr = 0; rr < 4; ++rr) {
      int bl = bl0 + rr;
      int b = bl / LL, l = bl - (bl / LL)*LL;
      float rr0 = r[(bl*3 + 0)*3 + c];
      float rr1 = r[(bl*3 + 1)*3 + c];
      float rr2 = r[(bl*3 + 2)*3 + c];
      float tt  = tvec[bl*3 + c];
      int prow = (b*NH + np)*LL + l;
      qp[prow*12 + p*3 + c] = yq[rr][base]*rr0 + yq[rr][base+1]*rr1 + yq[rr][base+2]*rr2 + tt;
      kp[prow*12 + p*3 + c] = yk[rr][base]*rr0 + yk[rr][base+1]*rr1 + yk[rr][base+2]*rr2 + tt;
      vp[prow*12 + p*3 + c] = yv[rr][base]*rr0 + yv[rr][base+1]*rr1 + yv[rr][base+2]*rr2 + tt;
    }
  }
}

// ---------------- K2: fused bias + logits + softmax + attn@V + attn@e + point epilogue
// one block per (b,i); grid 768, block 256
__global__ __launch_bounds__(256) void k_fused(
    fp32p e, fp32p Wb, fp32p gamma, fp32p r, fp32p tvec,
    const float* qs, const float* ks, const float* vs,
    const float* qp, const float* kp, const float* vp,
    float* cat)
{
  int bi = blockIdx.x;                 // b*LL + i
  int b = bi / LL, i = bi - (bi / LL)*LL;
  int t = threadIdx.x;
  __shared__ float attnS[8*385];       // stride 385: odd -> conflict-free
  __shared__ float redS[128*9];
  __shared__ float opS[96];

  const float* ebase = e + (size_t)bi*LL*128;

  // ---- phase 1: logits (bias + scalar dot + point dist) -> attnS ----
  for (int j = t; j < LL; j += 256) {
    const float4* er = reinterpret_cast<const float4*>(ebase + j*128);
    float accb[8] = {0,0,0,0,0,0,0,0};
    for (int it = 0; it < 32; ++it) {
      float4 v4 = er[it];
      float vv[4] = {v4.x, v4.y, v4.z, v4.w};
      #pragma unroll
      for (int k = 0; k < 4; ++k) {
        float ev = vv[k];
        int d = it*4 + k;
        #pragma unroll
        for (int nn = 0; nn < 8; ++nn) accb[nn] += ev * Wb[d*8 + nn];  // uniform -> s_load
      }
    }
    #pragma unroll
    for (int nn = 0; nn < 8; ++nn) {
      int rowq = (b*NH + nn)*LL + i;   // wave-uniform
      int rowk = (b*NH + nn)*LL + j;   // per-lane
      const float4* k4  = reinterpret_cast<const float4*>(ks + (size_t)rowk*16);
      const float4* q4  = reinterpret_cast<const float4*>(qs + (size_t)rowq*16);
      float dots = 0.f;
      #pragma unroll
      for (int k2 = 0; k2 < 4; ++k2) {
        float4 kv = k4[k2]; float4 qv = q4[k2];
        dots += qv.x*kv.x + qv.y*kv.y + qv.z*kv.z + qv.w*kv.w;
      }
      const float4* kp4 = reinterpret_cast<const float4*>(kp + (size_t)rowk*12);
      const float4* qp4 = reinterpret_cast<const float4*>(qp + (size_t)rowq*12);
      float cross = 0.f, kk = 0.f, qq = 0.f;
      #pragma unroll
      for (int k2 = 0; k2 < 3; ++k2) {
        float4 pv = kp4[k2]; float4 qv = qp4[k2];
        cross += qv.x*pv.x + qv.y*pv.y + qv.z*pv.z + qv.w*pv.w;
        kk += pv.x*pv.x + pv.y*pv.y + pv.z*pv.z + pv.w*pv.w;
        qq += qv.x*qv.x + qv.y*qv.y + qv.z*qv.z + qv.w*qv.w;
      }
      float coef = -0.125f * gamma[nn];
      attnS[nn*385 + j] = 0.57735027f * (0.25f*dots + accb[nn] + coef*(qq + kk - 2.f*cross));
    }
  }
  __syncthreads();

  // ---- softmax: wave w handles heads 2w, 2w+1 ----
  {
    int wv = t >> 6, lane = t & 63;
    #pragma unroll
    for (int nn2 = 0; nn2 < 2; ++nn2) {
      int n = wv*2 + nn2;
      float v[6];
      #pragma unroll
      for (int q = 0; q < 6; ++q) v[q] = attnS[n*385 + lane + q*64];
      float m = v[0];
      #pragma unroll
      for (int q = 1; q < 6; ++q) m = fmaxf(m, v[q]);
      #pragma unroll
      for (int off = 32; off >= 1; off >>= 1) m = fmaxf(m, __shfl_xor(m, off, 64));
      float s = 0.f;
      #pragma unroll
      for (int q = 0; q < 6; ++q) { v[q] = __expf(v[q] - m); s += v[q]; }
      #pragma unroll
      for (int off = 32; off >= 1; off >>= 1) s += __shfl_xor(s, off, 64);
      float inv = 1.f / s;
      #pragma unroll
      for (int q = 0; q < 6; ++q) attnS[n*385 + lane + q*64] = v[q]*inv;
    }
  }
  __syncthreads();

  // ---- phase 2: out_scalar = attn@vs -> cat; op = attn@vp -> opS ----
  if (t < 224) {
    int n = t / 28, d = t - (t / 28)*28;
    const float* an = attnS + n*385;
    int rowbase = (b*NH + n)*LL;
    float acc = 0.f;
    if (d < 16) {
      const float* src = vs + (size_t)rowbase*16 + d;
      for (int j = 0; j < LL; ++j) acc += an[j] * src[j*16];
      cat[(size_t)bi*1280 + n*16 + d] = acc;
    } else {
      const float* src = vp + (size_t)rowbase*12 + (d - 16);
      for (int j = 0; j < LL; ++j) acc += an[j] * src[j*12];
      opS[n*12 + (d - 16)] = acc;
    }
  }
  __syncthreads();

  // ---- phase 3: out_pair = attn . e  (re-stream e row; LLC-resident) ----
  {
    int oct = t & 15, n3 = (t >> 4) & 7, half = t >> 7;
    const float* an = attnS + n3*385;
    const float4* e4 = reinterpret_cast<const float4*>(ebase);
    float acc[8] = {0,0,0,0,0,0,0,0};
    for (int jj = 0; jj < 192; ++jj) {
      int j = 2*jj + half;
      float4 va = e4[j*32 + oct*2];
      float4 vb = e4[j*32 + oct*2 + 1];
      float a = an[j];
      acc[0] += a*va.x; acc[1] += a*va.y; acc[2] += a*va.z; acc[3] += a*va.w;
      acc[4] += a*vb.x; acc[5] += a*vb.y; acc[6] += a*vb.z; acc[7] += a*vb.w;
    }
    if (half) {
      #pragma unroll
      for (int k = 0; k < 8; ++k) redS[(t - 128)*9 + k] = acc[k];
    }
    __syncthreads();
    if (!half) {
      float* dst = cat + (size_t)bi*1280 + 128 + n3*128 + oct*8;
      #pragma unroll
      for (int k = 0; k < 8; ++k) dst[k] = acc[k] + redS[t*9 + k];
    }
  }

  // ---- phase 4: point epilogue (opS ready since phase-2 barrier) ----
  if (t < 32) {
    int n = t >> 2, p = t & 3;
    float o[3];
    #pragma unroll
    for (int k = 0; k < 3; ++k) o[k] = opS[n*12 + p*3 + k] - tvec[bi*3 + k];
    float loc[3];
    #pragma unroll
    for (int c = 0; c < 3; ++c) {
      float s = 0.f;
      #pragma unroll
      for (int k = 0; k < 3; ++k) s += o[k] * r[(bi*3 + c)*3 + k];   // r[b,i,c,k]
      loc[c] = s;
    }
    float* dst = cat + (size_t)bi*1280;
    dst[1152 + n*12 + p*3 + 0] = loc[0];
    dst[1152 + n*12 + p*3 + 1] = loc[1];
    dst[1152 + n*12 + p*3 + 2] = loc[2];
    dst[1248 + n*4 + p] = sqrtf(loc[0]*loc[0] + loc[1]*loc[1] + loc[2]*loc[2]);
  }
}

// ---------------- K3: out = cat @ Wo + bo ----------------
// 4 rows per block, block 256 (split-K halves), grid 192
__global__ __launch_bounds__(256) void k_out(const float* cat, fp32p Wo, fp32p bo,
                                             float* out)
{
  int r0 = blockIdx.x*4;
  int t = threadIdx.x;
  __shared__ float catS[4*1280];
  __shared__ float redO[4*128];
  for (int idx = t; idx < 4*1280; idx += 256)
    catS[idx] = cat[(size_t)r0*1280 + idx];
  __syncthreads();
  int c = t & 127, half = t >> 7;
  int k0 = half*640;
  float a0 = 0.f, a1 = 0.f, a2 = 0.f, a3 = 0.f;
  for (int k = k0; k < k0 + 640; ++k) {
    float w = Wo[k*128 + c];
    a0 += catS[k]        * w;
    a1 += catS[1280 + k] * w;
    a2 += catS[2560 + k] * w;
    a3 += catS[3840 + k] * w;
  }
  if (half) { redO[c] = a0; redO[128 + c] = a1; redO[256 + c] = a2; redO[384 + c] = a3; }
  __syncthreads();
  if (!half) {
    float bv = bo[c];
    out[(size_t)(r0 + 0)*128 + c] = a0 + redO[c]       + bv;
    out[(size_t)(r0 + 1)*128 + c] = a1 + redO[128 + c] + bv;
    out[(size_t)(r0 + 2)*128 + c] = a2 + redO[256 + c] + bv;
    out[(size_t)(r0 + 3)*128 + c] = a3 + redO[384 + c] + bv;
  }
}

extern "C" void kernel_launch(void* const* d_in, const int* in_sizes, int n_in,
                              void* d_out, int out_size, void* d_ws, size_t ws_size,
                              hipStream_t stream)
{
  fp32p x    = (fp32p)d_in[0];
  fp32p e    = (fp32p)d_in[1];
  fp32p r    = (fp32p)d_in[2];
  fp32p tv   = (fp32p)d_in[3];
  fp32p Wqs  = (fp32p)d_in[4];
  fp32p Wks  = (fp32p)d_in[5];
  fp32p Wvs  = (fp32p)d_in[6];
  fp32p Wb   = (fp32p)d_in[7];
  fp32p Wqp  = (fp32p)d_in[8];
  fp32p Wkp  = (fp32p)d_in[9];
  fp32p Wvp  = (fp32p)d_in[10];
  fp32p gam  = (fp32p)d_in[11];
  fp32p Wo   = (fp32p)d_in[12];
  fp32p bo   = (fp32p)d_in[13];
  float* out = (float*)d_out;

  // ws partition (floats); ~3.5 MB
  float* qs  = (float*)d_ws;
  float* ks  = qs + 98304;             // 6144*16
  float* vs  = ks + 98304;
  float* qp  = vs + 98304;             // 6144*12
  float* kp  = qp + 73728;
  float* vp  = kp + 73728;
  float* cat = vp + 73728;             // 768*1280

  k_proj<<<192, 128, 0, stream>>>(x, r, tv, Wqs, Wks, Wvs, Wqp, Wkp, Wvp,
                                  qs, ks, vs, qp, kp, vp);
  k_fused<<<768, 256, 0, stream>>>(e, Wb, gam, r, tv, qs, ks, vs, qp, kp, vp, cat);
  k_out<<<192, 256, 0, stream>>>(cat, Wo, bo, out);
}

// Round 6
// 450.661 us; speedup vs baseline: 1.3430x; 1.3430x over previous
//
#include <hip/hip_runtime.h>

#define LL 384
#define NH 8

typedef const float* fp32p;

// ---------------- K1: projections + point rotation ----------------
// 4 rows per block, block 128, grid 192
__global__ __launch_bounds__(128) void k_proj(
    fp32p x, fp32p r, fp32p tvec,
    fp32p Wqs, fp32p Wks, fp32p Wvs,
    fp32p Wqp, fp32p Wkp, fp32p Wvp,
    float* qs, float* ks, float* vs,
    float* qp, float* kp, float* vp)
{
  int t = threadIdx.x;
  int bl0 = blockIdx.x * 4;
  __shared__ float xs[4][128];
  __shared__ float yq[4][96], yk[4][96], yv[4][96];
  #pragma unroll
  for (int rr = 0; rr < 4; ++rr) xs[rr][t] = x[(bl0 + rr)*128 + t];
  __syncthreads();
  float aq[4] = {0,0,0,0}, ak[4] = {0,0,0,0}, av[4] = {0,0,0,0};
  float pq[4] = {0,0,0,0}, pk[4] = {0,0,0,0}, pv[4] = {0,0,0,0};
  bool pt_act = (t < 96);
  for (int d = 0; d < 128; ++d) {
    float wq = Wqs[d*128 + t], wk = Wks[d*128 + t], wv = Wvs[d*128 + t];
    #pragma unroll
    for (int rr = 0; rr < 4; ++rr) {
      float xv = xs[rr][d];
      aq[rr] += xv*wq; ak[rr] += xv*wk; av[rr] += xv*wv;
    }
    if (pt_act) {
      float uq = Wqp[d*96 + t], uk = Wkp[d*96 + t], uv = Wvp[d*96 + t];
      #pragma unroll
      for (int rr = 0; rr < 4; ++rr) {
        float xv = xs[rr][d];
        pq[rr] += xv*uq; pk[rr] += xv*uk; pv[rr] += xv*uv;
      }
    }
  }
  int n = t >> 4, dhs = t & 15;
  #pragma unroll
  for (int rr = 0; rr < 4; ++rr) {
    int bl = bl0 + rr;
    int b = bl / LL, l = bl - (bl / LL)*LL;
    int rowbase = (b*NH + n)*LL + l;
    qs[rowbase*16 + dhs] = aq[rr];
    ks[rowbase*16 + dhs] = ak[rr];
    vs[rowbase*16 + dhs] = av[rr];
  }
  if (pt_act) {
    #pragma unroll
    for (int rr = 0; rr < 4; ++rr) { yq[rr][t] = pq[rr]; yk[rr][t] = pk[rr]; yv[rr][t] = pv[rr]; }
  }
  __syncthreads();
  if (pt_act) {
    int np = t / 12;
    int rem = t - np*12;
    int p = rem / 3, c = rem - p*3;
    int base = np*12 + p*3;
    #pragma unroll
    for (int rr = 0; rr < 4; ++rr) {
      int bl = bl0 + rr;
      int b = bl / LL, l = bl - (bl / LL)*LL;
      float rr0 = r[(bl*3 + 0)*3 + c];
      float rr1 = r[(bl*3 + 1)*3 + c];
      float rr2 = r[(bl*3 + 2)*3 + c];
      float tt  = tvec[bl*3 + c];
      int prow = (b*NH + np)*LL + l;
      qp[prow*12 + p*3 + c] = yq[rr][base]*rr0 + yq[rr][base+1]*rr1 + yq[rr][base+2]*rr2 + tt;
      kp[prow*12 + p*3 + c] = yk[rr][base]*rr0 + yk[rr][base+1]*rr1 + yk[rr][base+2]*rr2 + tt;
      vp[prow*12 + p*3 + c] = yv[rr][base]*rr0 + yv[rr][base+1]*rr1 + yv[rr][base+2]*rr2 + tt;
    }
  }
}

// ---------------- K2: bias_pair = e @ Wb  (writes (B,N,L,L) fp32) ----------------
// one thread per (b,i,j); grid 1152, block 256
__global__ __launch_bounds__(256) void k_bias(fp32p e, fp32p Wb, float* bias)
{
  __shared__ float WbS[128*8];
  for (int idx = threadIdx.x; idx < 1024; idx += 256) WbS[idx] = Wb[idx];
  __syncthreads();
  int tid = blockIdx.x*256 + threadIdx.x;          // enumerates (b,i,j)
  int b = tid / (LL*LL);
  int rem = tid - b*(LL*LL);
  int i = rem / LL, j = rem - (rem / LL)*LL;
  const float4* erow = reinterpret_cast<const float4*>(e) + (size_t)tid * 32;
  float acc[8] = {0,0,0,0,0,0,0,0};
  for (int it = 0; it < 32; ++it) {
    float4 v4 = erow[it];
    float vv[4] = {v4.x, v4.y, v4.z, v4.w};
    #pragma unroll
    for (int k = 0; k < 4; ++k) {
      float v = vv[k];
      const float* wr = &WbS[(it*4 + k)*8];
      #pragma unroll
      for (int nn = 0; nn < 8; ++nn) acc[nn] += v * wr[nn];
    }
  }
  #pragma unroll
  for (int nn = 0; nn < 8; ++nn)
    bias[(((size_t)(b*NH + nn)*LL + i)*LL) + j] = acc[nn];
}

// ---------------- K3: logits + softmax (in-place bias -> attn) ----------------
// one wave per (b,n,i); grid 1536, block 256 (4 waves)
__global__ __launch_bounds__(256) void k_attn(
    const float* qs, const float* ks, const float* qp, const float* kp,
    fp32p gamma, float* attn)
{
  int row = blockIdx.x*4 + (threadIdx.x >> 6);     // (b,n,i)
  int lane = threadIdx.x & 63;
  int bn = row / LL;
  int n = bn & 7;
  int rowbase = bn * LL;
  float q[16];
  const float4* q4 = reinterpret_cast<const float4*>(qs + (size_t)row*16);
  #pragma unroll
  for (int k2 = 0; k2 < 4; ++k2) { float4 v = q4[k2]; q[4*k2]=v.x; q[4*k2+1]=v.y; q[4*k2+2]=v.z; q[4*k2+3]=v.w; }
  float qpv[12];
  const float4* p4 = reinterpret_cast<const float4*>(qp + (size_t)row*12);
  #pragma unroll
  for (int k2 = 0; k2 < 3; ++k2) { float4 v = p4[k2]; qpv[4*k2]=v.x; qpv[4*k2+1]=v.y; qpv[4*k2+2]=v.z; qpv[4*k2+3]=v.w; }
  float qq = 0.f;
  #pragma unroll
  for (int k2 = 0; k2 < 12; ++k2) qq += qpv[k2]*qpv[k2];
  float coef = -0.125f * gamma[n];
  float lg[6];
  float* arow = attn + (size_t)row*LL;
  #pragma unroll
  for (int jj = 0; jj < 6; ++jj) {
    int j = lane + jj*64;
    const float4* k4 = reinterpret_cast<const float4*>(ks + (size_t)(rowbase + j)*16);
    float dots = 0.f;
    #pragma unroll
    for (int k2 = 0; k2 < 4; ++k2) { float4 v = k4[k2]; dots += q[4*k2]*v.x + q[4*k2+1]*v.y + q[4*k2+2]*v.z + q[4*k2+3]*v.w; }
    const float4* kp4 = reinterpret_cast<const float4*>(kp + (size_t)(rowbase + j)*12);
    float cross = 0.f, kk = 0.f;
    #pragma unroll
    for (int k2 = 0; k2 < 3; ++k2) {
      float4 v = kp4[k2];
      cross += qpv[4*k2]*v.x + qpv[4*k2+1]*v.y + qpv[4*k2+2]*v.z + qpv[4*k2+3]*v.w;
      kk += v.x*v.x + v.y*v.y + v.z*v.z + v.w*v.w;
    }
    float bs = arow[j];
    lg[jj] = 0.57735027f * (0.25f*dots + bs + coef*(qq + kk - 2.f*cross));
  }
  float m = lg[0];
  #pragma unroll
  for (int jj = 1; jj < 6; ++jj) m = fmaxf(m, lg[jj]);
  #pragma unroll
  for (int off = 32; off >= 1; off >>= 1) m = fmaxf(m, __shfl_xor(m, off, 64));
  float el[6]; float s = 0.f;
  #pragma unroll
  for (int jj = 0; jj < 6; ++jj) { el[jj] = __expf(lg[jj] - m); s += el[jj]; }
  #pragma unroll
  for (int off = 32; off >= 1; off >>= 1) s += __shfl_xor(s, off, 64);
  float inv = 1.f / s;
  #pragma unroll
  for (int jj = 0; jj < 6; ++jj) arow[lane + jj*64] = el[jj]*inv;
}

// ---------------- K4a: out_scalar = attn@vs, op = attn@vp ----------------
// thread per (row, dim32); grid 768, block 256
__global__ __launch_bounds__(256) void k_av(
    const float* attn, const float* vs, const float* vp, float* cat, float* opb)
{
  int tid = blockIdx.x*256 + threadIdx.x;
  int row = tid >> 5;
  int dim = tid & 31;
  if (dim >= 28) return;
  int i = row % LL;
  int bn = row / LL;
  int rowbase = bn * LL;
  const float* arow = attn + (size_t)row*LL;
  const float* src; int stride;
  if (dim < 16) { src = vs + (size_t)rowbase*16 + dim; stride = 16; }
  else          { src = vp + (size_t)rowbase*12 + (dim - 16); stride = 12; }
  float acc = 0.f;
  for (int j = 0; j < LL; ++j) acc += arow[j] * src[(size_t)j*stride];
  int b = bn >> 3, n = bn & 7;
  if (dim < 16) cat[((size_t)(b*LL + i))*1280 + n*16 + dim] = acc;
  else          opb[(size_t)row*12 + (dim - 16)] = acc;
}

// ---------------- K4b: out_pair = attn . e   (block per (b,i)) ----------------
__global__ __launch_bounds__(256) void k_pair(fp32p e, const float* attn, float* cat)
{
  int bi = blockIdx.x;                 // b*L + i
  int b = bi / LL, i = bi - (bi / LL)*LL;
  __shared__ float attnS[8*384];
  __shared__ float redS[128*9];
  for (int idx = threadIdx.x; idx < 8*384; idx += 256) {
    int n = idx / 384, j = idx - n*384;
    attnS[idx] = attn[(((size_t)(b*NH + n)*LL + i)*LL) + j];
  }
  __syncthreads();
  int t = threadIdx.x;
  int oct = t & 15;                    // which 8-float chunk of d
  int n = (t >> 4) & 7;
  int half = t >> 7;
  const float4* ebase = reinterpret_cast<const float4*>(e) + (size_t)bi*LL*32;
  const float* an = attnS + n*384;
  float acc[8] = {0,0,0,0,0,0,0,0};
  for (int jj = 0; jj < 192; ++jj) {
    int j = 2*jj + half;
    float4 va = ebase[j*32 + oct*2];
    float4 vb = ebase[j*32 + oct*2 + 1];
    float a = an[j];
    acc[0] += a * va.x; acc[1] += a * va.y; acc[2] += a * va.z; acc[3] += a * va.w;
    acc[4] += a * vb.x; acc[5] += a * vb.y; acc[6] += a * vb.z; acc[7] += a * vb.w;
  }
  if (half) {
    #pragma unroll
    for (int k = 0; k < 8; ++k) redS[(t - 128)*9 + k] = acc[k];
  }
  __syncthreads();
  if (!half) {
    float* dst = cat + (size_t)bi*1280 + 128 + n*128 + oct*8;
    #pragma unroll
    for (int k = 0; k < 8; ++k) dst[k] = acc[k] + redS[t*9 + k];
  }
}

// ---------------- K5: inverse point transform + norms ----------------
// op_local[c] = sum_k (op - t)[k] * r[b,i,c,k]   (einsum 'bnipk,bick->bnipc')
__global__ __launch_bounds__(256) void k_pt(const float* opb, fp32p r, fp32p tvec, float* cat)
{
  int tid = blockIdx.x*256 + threadIdx.x;    // 24576
  int p = tid & 3;
  int row = tid >> 2;
  int i = row % LL;
  int bn = row / LL;
  int b = bn >> 3, n = bn & 7;
  int bi = b*LL + i;
  float o[3];
  #pragma unroll
  for (int k = 0; k < 3; ++k)
    o[k] = opb[(size_t)row*12 + p*3 + k] - tvec[bi*3 + k];
  float loc[3];
  #pragma unroll
  for (int c = 0; c < 3; ++c) {
    float s = 0.f;
    #pragma unroll
    for (int k = 0; k < 3; ++k) s += o[k] * r[(bi*3 + c)*3 + k];   // r[b,i,c,k]
    loc[c] = s;
  }
  float* dst = cat + (size_t)bi*1280;
  dst[1152 + n*12 + p*3 + 0] = loc[0];
  dst[1152 + n*12 + p*3 + 1] = loc[1];
  dst[1152 + n*12 + p*3 + 2] = loc[2];
  dst[1248 + n*4 + p] = sqrtf(loc[0]*loc[0] + loc[1]*loc[1] + loc[2]*loc[2]);
}

// ---------------- K6: out = cat @ Wo + bo ----------------
// 8 rows/block, grid 96, block 256. Thread owns float4 of cols; K unrolled x16
// -> 16 independent dwordx4 loads in flight (fixes the 232us latency chain).
__global__ __launch_bounds__(256) void k_out(const float* cat, fp32p Wo, fp32p bo,
                                             float* out)
{
  int r0 = blockIdx.x * 8;
  int t = threadIdx.x;
  __shared__ float catS[8*1280];       // 40 KB
  {
    const float4* c4 = reinterpret_cast<const float4*>(cat + (size_t)r0*1280);
    float4* s4 = reinterpret_cast<float4*>(catS);
    for (int idx = t; idx < 2560; idx += 256) s4[idx] = c4[idx];
  }
  __syncthreads();
  int row = t >> 5;                    // 0..7
  int cg  = t & 31;                    // col group (4 cols)
  const float* crow = catS + row*1280;
  const float4* w4 = reinterpret_cast<const float4*>(Wo) + cg;   // + k*32 per k
  float ax = 0.f, ay = 0.f, az = 0.f, aw = 0.f;
  for (int k = 0; k < 1280; k += 16) {
    float4 w[16]; float a[16];
    #pragma unroll
    for (int u = 0; u < 16; ++u) { w[u] = w4[(k + u)*32]; a[u] = crow[k + u]; }
    #pragma unroll
    for (int u = 0; u < 16; ++u) {
      ax += a[u]*w[u].x; ay += a[u]*w[u].y; az += a[u]*w[u].z; aw += a[u]*w[u].w;
    }
  }
  float4 bv = reinterpret_cast<const float4*>(bo)[cg];
  float4 res = { ax + bv.x, ay + bv.y, az + bv.z, aw + bv.w };
  reinterpret_cast<float4*>(out + (size_t)(r0 + row)*128)[cg] = res;
}

extern "C" void kernel_launch(void* const* d_in, const int* in_sizes, int n_in,
                              void* d_out, int out_size, void* d_ws, size_t ws_size,
                              hipStream_t stream)
{
  fp32p x    = (fp32p)d_in[0];
  fp32p e    = (fp32p)d_in[1];
  fp32p r    = (fp32p)d_in[2];
  fp32p tv   = (fp32p)d_in[3];
  fp32p Wqs  = (fp32p)d_in[4];
  fp32p Wks  = (fp32p)d_in[5];
  fp32p Wvs  = (fp32p)d_in[6];
  fp32p Wb   = (fp32p)d_in[7];
  fp32p Wqp  = (fp32p)d_in[8];
  fp32p Wkp  = (fp32p)d_in[9];
  fp32p Wvp  = (fp32p)d_in[10];
  fp32p gam  = (fp32p)d_in[11];
  fp32p Wo   = (fp32p)d_in[12];
  fp32p bo   = (fp32p)d_in[13];
  float* out = (float*)d_out;

  // ws partition (floats); total ~15.7 MB
  float* qs   = (float*)d_ws;
  float* ks   = qs + 98304;            // 6144*16
  float* vs   = ks + 98304;
  float* qp   = vs + 98304;            // 6144*12
  float* kp   = qp + 73728;
  float* vp   = kp + 73728;
  float* attn = vp + 73728;            // 2*8*384*384 (bias written here, softmaxed in place)
  float* opb  = attn + 2359296;        // 6144*12
  float* cat  = opb + 73728;           // 768*1280

  k_proj<<<192, 128, 0, stream>>>(x, r, tv, Wqs, Wks, Wvs, Wqp, Wkp, Wvp,
                                  qs, ks, vs, qp, kp, vp);
  k_bias<<<1152, 256, 0, stream>>>(e, Wb, attn);
  k_attn<<<1536, 256, 0, stream>>>(qs, ks, qp, kp, gam, attn);
  k_av<<<768, 256, 0, stream>>>(attn, vs, vp, cat, opb);
  k_pair<<<768, 256, 0, stream>>>(e, attn, cat);
  k_pt<<<96, 256, 0, stream>>>(opb, r, tv, cat);
  k_out<<<96, 256, 0, stream>>>(cat, Wo, bo, out);
}

// Round 7
// 439.658 us; speedup vs baseline: 1.3766x; 1.0250x over previous
//
#include <hip/hip_runtime.h>

#define LL 384
#define NH 8

typedef const float* fp32p;

// ---------------- K1: projections + point rotation ----------------
// grid 768 (b*L+l), block 128
__global__ __launch_bounds__(128) void k_proj(
    fp32p x, fp32p r, fp32p tvec,
    fp32p Wqs, fp32p Wks, fp32p Wvs,
    fp32p Wqp, fp32p Wkp, fp32p Wvp,
    float* qs, float* ks, float* vs,
    float* qp, float* kp, float* vp)
{
  int bl = blockIdx.x;
  int t = threadIdx.x;
  __shared__ float xs[128];
  __shared__ float yq[96], yk[96], yv[96];
  xs[t] = x[bl*128 + t];
  __syncthreads();
  float aq = 0.f, ak = 0.f, av = 0.f;
  #pragma unroll 4
  for (int d = 0; d < 128; ++d) {
    float xv = xs[d];
    aq += xv * Wqs[d*128 + t];
    ak += xv * Wks[d*128 + t];
    av += xv * Wvs[d*128 + t];
  }
  int b = bl / LL, l = bl - (bl / LL) * LL;
  int n = t >> 4, dhs = t & 15;
  int rowbase = (b*NH + n)*LL + l;
  qs[rowbase*16 + dhs] = aq;
  ks[rowbase*16 + dhs] = ak;
  vs[rowbase*16 + dhs] = av;
  if (t < 96) {
    float pq = 0.f, pk = 0.f, pv = 0.f;
    #pragma unroll 4
    for (int d = 0; d < 128; ++d) {
      float xv = xs[d];
      pq += xv * Wqp[d*96 + t];
      pk += xv * Wkp[d*96 + t];
      pv += xv * Wvp[d*96 + t];
    }
    yq[t] = pq; yk[t] = pk; yv[t] = pv;
  }
  __syncthreads();
  if (t < 96) {
    int np = t / 12;
    int rem = t - np*12;
    int p = rem / 3, c = rem - p*3;
    float rr0 = r[(bl*3 + 0)*3 + c];
    float rr1 = r[(bl*3 + 1)*3 + c];
    float rr2 = r[(bl*3 + 2)*3 + c];
    float tt  = tvec[bl*3 + c];
    int base = np*12 + p*3;
    int prow = (b*NH + np)*LL + l;
    qp[prow*12 + p*3 + c] = yq[base]*rr0 + yq[base+1]*rr1 + yq[base+2]*rr2 + tt;
    kp[prow*12 + p*3 + c] = yk[base]*rr0 + yk[base+1]*rr1 + yk[base+2]*rr2 + tt;
    vp[prow*12 + p*3 + c] = yv[base]*rr0 + yv[base+1]*rr1 + yv[base+2]*rr2 + tt;
  }
}

// ---------------- K2: fused bias+logits+softmax+attn@V+attn@e+point ----------------
// one block per (b,i); grid 768, block 256
__global__ __launch_bounds__(256) void k_fused(
    fp32p e, fp32p Wb, fp32p gamma, fp32p r, fp32p tvec,
    const float* qs, const float* ks, const float* vs,
    const float* qp, const float* kp, const float* vp,
    float* cat)
{
  int bi = blockIdx.x;                 // b*LL + i
  int b = bi / LL, i = bi - (bi / LL)*LL;
  int t = threadIdx.x;
  __shared__ float attnS[8*385];       // stride 385 -> conflict-free
  __shared__ float WbS[1024];
  __shared__ float qS[128];            // 8 heads x 16
  __shared__ float qpS[96];            // 8 heads x 12
  __shared__ float qqS[8], coefS[8];
  __shared__ float redS[128*9];
  __shared__ float opS[96];

  const float* ebase = e + (size_t)bi*LL*128;

  // ---- phase 0: stage Wb, q rows ----
  #pragma unroll
  for (int u = 0; u < 4; ++u) WbS[t + u*256] = Wb[t + u*256];
  if (t < 128) {
    int n = t >> 4, d = t & 15;
    qS[t] = qs[(size_t)(((b*NH + n)*LL + i))*16 + d];
  } else if (t < 224) {
    int tt = t - 128;
    int n = tt / 12, d = tt - n*12;
    qpS[tt] = qp[(size_t)(((b*NH + n)*LL + i))*12 + d];
  } else if (t < 232) {
    coefS[t - 224] = -0.125f * gamma[t - 224];
  }
  __syncthreads();

  // ---- phase 1a: bias = e(row) @ Wb -> attnS; qq per head ----
  if (t < 192) {
    const float4* er0 = reinterpret_cast<const float4*>(ebase + (size_t)t*128);
    const float4* er1 = reinterpret_cast<const float4*>(ebase + (size_t)(t + 192)*128);
    float acc0[8] = {0,0,0,0,0,0,0,0};
    float acc1[8] = {0,0,0,0,0,0,0,0};
    for (int d4 = 0; d4 < 32; ++d4) {
      float4 e0 = er0[d4], e1 = er1[d4];
      float a0[4] = {e0.x, e0.y, e0.z, e0.w};
      float a1[4] = {e1.x, e1.y, e1.z, e1.w};
      #pragma unroll
      for (int k = 0; k < 4; ++k) {
        int d = d4*4 + k;
        float4 w0 = *reinterpret_cast<const float4*>(&WbS[d*8]);
        float4 w1 = *reinterpret_cast<const float4*>(&WbS[d*8 + 4]);
        acc0[0] += a0[k]*w0.x; acc0[1] += a0[k]*w0.y; acc0[2] += a0[k]*w0.z; acc0[3] += a0[k]*w0.w;
        acc0[4] += a0[k]*w1.x; acc0[5] += a0[k]*w1.y; acc0[6] += a0[k]*w1.z; acc0[7] += a0[k]*w1.w;
        acc1[0] += a1[k]*w0.x; acc1[1] += a1[k]*w0.y; acc1[2] += a1[k]*w0.z; acc1[3] += a1[k]*w0.w;
        acc1[4] += a1[k]*w1.x; acc1[5] += a1[k]*w1.y; acc1[6] += a1[k]*w1.z; acc1[7] += a1[k]*w1.w;
      }
    }
    #pragma unroll
    for (int n = 0; n < 8; ++n) {
      attnS[n*385 + t]       = acc0[n];
      attnS[n*385 + t + 192] = acc1[n];
    }
  } else if (t < 200) {
    int n = t - 192;
    float s = 0.f;
    #pragma unroll
    for (int k = 0; k < 12; ++k) { float v = qpS[n*12 + k]; s += v*v; }
    qqS[n] = s;
  }
  __syncthreads();

  // ---- phase 1b: logits ----
  if (t < 192) {
    #pragma unroll
    for (int n = 0; n < 8; ++n) {
      int bn = b*NH + n;
      float4 q0 = *reinterpret_cast<const float4*>(&qS[n*16]);
      float4 q1 = *reinterpret_cast<const float4*>(&qS[n*16 + 4]);
      float4 q2 = *reinterpret_cast<const float4*>(&qS[n*16 + 8]);
      float4 q3 = *reinterpret_cast<const float4*>(&qS[n*16 + 12]);
      float4 p0 = *reinterpret_cast<const float4*>(&qpS[n*12]);
      float4 p1 = *reinterpret_cast<const float4*>(&qpS[n*12 + 4]);
      float4 p2 = *reinterpret_cast<const float4*>(&qpS[n*12 + 8]);
      float qq = qqS[n], coef = coefS[n];
      #pragma unroll
      for (int jj = 0; jj < 2; ++jj) {
        int j = t + jj*192;
        size_t rowk = (size_t)bn*LL + j;
        const float4* k4  = reinterpret_cast<const float4*>(ks + rowk*16);
        const float4* kp4 = reinterpret_cast<const float4*>(kp + rowk*12);
        float4 k0 = k4[0], k1 = k4[1], k2 = k4[2], k3 = k4[3];
        float dots = q0.x*k0.x + q0.y*k0.y + q0.z*k0.z + q0.w*k0.w
                   + q1.x*k1.x + q1.y*k1.y + q1.z*k1.z + q1.w*k1.w
                   + q2.x*k2.x + q2.y*k2.y + q2.z*k2.z + q2.w*k2.w
                   + q3.x*k3.x + q3.y*k3.y + q3.z*k3.z + q3.w*k3.w;
        float4 c0 = kp4[0], c1 = kp4[1], c2 = kp4[2];
        float cross = p0.x*c0.x + p0.y*c0.y + p0.z*c0.z + p0.w*c0.w
                    + p1.x*c1.x + p1.y*c1.y + p1.z*c1.z + p1.w*c1.w
                    + p2.x*c2.x + p2.y*c2.y + p2.z*c2.z + p2.w*c2.w;
        float kk = c0.x*c0.x + c0.y*c0.y + c0.z*c0.z + c0.w*c0.w
                 + c1.x*c1.x + c1.y*c1.y + c1.z*c1.z + c1.w*c1.w
                 + c2.x*c2.x + c2.y*c2.y + c2.z*c2.z + c2.w*c2.w;
        float bs = attnS[n*385 + j];
        attnS[n*385 + j] = 0.57735027f * (0.25f*dots + bs + coef*(qq + kk - 2.f*cross));
      }
    }
  }
  __syncthreads();

  // ---- softmax: wave w handles heads 2w, 2w+1 ----
  {
    int wv = t >> 6, lane = t & 63;
    #pragma unroll
    for (int nn2 = 0; nn2 < 2; ++nn2) {
      int n = wv*2 + nn2;
      float v[6];
      #pragma unroll
      for (int q = 0; q < 6; ++q) v[q] = attnS[n*385 + lane + q*64];
      float m = v[0];
      #pragma unroll
      for (int q = 1; q < 6; ++q) m = fmaxf(m, v[q]);
      #pragma unroll
      for (int off = 32; off >= 1; off >>= 1) m = fmaxf(m, __shfl_xor(m, off, 64));
      float s = 0.f;
      #pragma unroll
      for (int q = 0; q < 6; ++q) { v[q] = __expf(v[q] - m); s += v[q]; }
      #pragma unroll
      for (int off = 32; off >= 1; off >>= 1) s += __shfl_xor(s, off, 64);
      float inv = 1.f / s;
      #pragma unroll
      for (int q = 0; q < 6; ++q) attnS[n*385 + lane + q*64] = v[q]*inv;
    }
  }
  __syncthreads();

  // ---- phase 2: out_scalar = attn@vs -> cat; op = attn@vp -> opS ----
  if (t < 224) {
    int n = t / 28, d = t - (t / 28)*28;
    const float* an = attnS + n*385;
    size_t rowbase = (size_t)(b*NH + n)*LL;
    float acc = 0.f;
    if (d < 16) {
      const float* src = vs + rowbase*16 + d;
      for (int j = 0; j < LL; ++j) acc += an[j] * src[j*16];
      cat[(size_t)bi*1280 + n*16 + d] = acc;
    } else {
      const float* src = vp + rowbase*12 + (d - 16);
      for (int j = 0; j < LL; ++j) acc += an[j] * src[j*12];
      opS[n*12 + (d - 16)] = acc;
    }
  }
  __syncthreads();

  // ---- phase 3: out_pair = attn . e  (e re-read; LLC-resident) ----
  {
    int oct = t & 15, n3 = (t >> 4) & 7, half = t >> 7;
    const float* an = attnS + n3*385;
    const float4* e4 = reinterpret_cast<const float4*>(ebase);
    float acc[8] = {0,0,0,0,0,0,0,0};
    for (int jj = 0; jj < 192; ++jj) {
      int j = 2*jj + half;
      float4 va = e4[j*32 + oct*2];
      float4 vb = e4[j*32 + oct*2 + 1];
      float a = an[j];
      acc[0] += a*va.x; acc[1] += a*va.y; acc[2] += a*va.z; acc[3] += a*va.w;
      acc[4] += a*vb.x; acc[5] += a*vb.y; acc[6] += a*vb.z; acc[7] += a*vb.w;
    }
    if (half) {
      #pragma unroll
      for (int k = 0; k < 8; ++k) redS[(t - 128)*9 + k] = acc[k];
    }
    __syncthreads();
    if (!half) {
      float* dst = cat + (size_t)bi*1280 + 128 + n3*128 + oct*8;
      #pragma unroll
      for (int k = 0; k < 8; ++k) dst[k] = acc[k] + redS[t*9 + k];
    }
  }

  // ---- phase 4: point epilogue ----
  if (t < 32) {
    int n = t >> 2, p = t & 3;
    float o[3];
    #pragma unroll
    for (int k = 0; k < 3; ++k) o[k] = opS[n*12 + p*3 + k] - tvec[bi*3 + k];
    float loc[3];
    #pragma unroll
    for (int c = 0; c < 3; ++c) {
      float s = 0.f;
      #pragma unroll
      for (int k = 0; k < 3; ++k) s += o[k] * r[(bi*3 + c)*3 + k];   // r[b,i,c,k]
      loc[c] = s;
    }
    float* dst = cat + (size_t)bi*1280;
    dst[1152 + n*12 + p*3 + 0] = loc[0];
    dst[1152 + n*12 + p*3 + 1] = loc[1];
    dst[1152 + n*12 + p*3 + 2] = loc[2];
    dst[1248 + n*4 + p] = sqrtf(loc[0]*loc[0] + loc[1]*loc[1] + loc[2]*loc[2]);
  }
}

// ---------------- K3: out = cat @ Wo + bo ----------------
// 8 rows/block, grid 96, block 256; 16-deep independent dwordx4 pipeline
__global__ __launch_bounds__(256) void k_out(const float* cat, fp32p Wo, fp32p bo,
                                             float* out)
{
  int r0 = blockIdx.x * 8;
  int t = threadIdx.x;
  __shared__ float catS[8*1280];       // 40 KB
  {
    const float4* c4 = reinterpret_cast<const float4*>(cat + (size_t)r0*1280);
    float4* s4 = reinterpret_cast<float4*>(catS);
    for (int idx = t; idx < 2560; idx += 256) s4[idx] = c4[idx];
  }
  __syncthreads();
  int row = t >> 5;                    // 0..7
  int cg  = t & 31;                    // col group (4 cols)
  const float* crow = catS + row*1280;
  const float4* w4 = reinterpret_cast<const float4*>(Wo) + cg;
  float ax = 0.f, ay = 0.f, az = 0.f, aw = 0.f;
  for (int k = 0; k < 1280; k += 16) {
    float4 w[16]; float a[16];
    #pragma unroll
    for (int u = 0; u < 16; ++u) { w[u] = w4[(k + u)*32]; a[u] = crow[k + u]; }
    #pragma unroll
    for (int u = 0; u < 16; ++u) {
      ax += a[u]*w[u].x; ay += a[u]*w[u].y; az += a[u]*w[u].z; aw += a[u]*w[u].w;
    }
  }
  float4 bv = reinterpret_cast<const float4*>(bo)[cg];
  float4 res = { ax + bv.x, ay + bv.y, az + bv.z, aw + bv.w };
  reinterpret_cast<float4*>(out + (size_t)(r0 + row)*128)[cg] = res;
}

extern "C" void kernel_launch(void* const* d_in, const int* in_sizes, int n_in,
                              void* d_out, int out_size, void* d_ws, size_t ws_size,
                              hipStream_t stream)
{
  fp32p x    = (fp32p)d_in[0];
  fp32p e    = (fp32p)d_in[1];
  fp32p r    = (fp32p)d_in[2];
  fp32p tv   = (fp32p)d_in[3];
  fp32p Wqs  = (fp32p)d_in[4];
  fp32p Wks  = (fp32p)d_in[5];
  fp32p Wvs  = (fp32p)d_in[6];
  fp32p Wb   = (fp32p)d_in[7];
  fp32p Wqp  = (fp32p)d_in[8];
  fp32p Wkp  = (fp32p)d_in[9];
  fp32p Wvp  = (fp32p)d_in[10];
  fp32p gam  = (fp32p)d_in[11];
  fp32p Wo   = (fp32p)d_in[12];
  fp32p bo   = (fp32p)d_in[13];
  float* out = (float*)d_out;

  // ws partition (floats); ~4.3 MB
  float* qs  = (float*)d_ws;
  float* ks  = qs + 98304;             // 6144*16
  float* vs  = ks + 98304;
  float* qp  = vs + 98304;             // 6144*12
  float* kp  = qp + 73728;
  float* vp  = kp + 73728;
  float* cat = vp + 73728;             // 768*1280

  k_proj<<<768, 128, 0, stream>>>(x, r, tv, Wqs, Wks, Wvs, Wqp, Wkp, Wvp,
                                  qs, ks, vs, qp, kp, vp);
  k_fused<<<768, 256, 0, stream>>>(e, Wb, gam, r, tv, qs, ks, vs, qp, kp, vp, cat);
  k_out<<<96, 256, 0, stream>>>(cat, Wo, bo, out);
}